// Round 5
// baseline (228.806 us; speedup 1.0000x reference)
//
#include <hip/hip_runtime.h>
#include <hip/hip_bf16.h>
#include <hip/hip_fp16.h>

// MHAHead B=8,S=2048,E=512. R10: rebalance fused mask-pack inside proj.
//   R9 post-mortem: proj 122us latency-bound -- z=3 mask-pack had only 512
//   blocks x 256 serial HBM-latency iterations/wave (~100us stragglers) while
//   GEMM blocks finished early. gemmS/gemmO improved (left top-5).
//   R10: flat 3584-block grid, roles interleaved 3 GEMM : 4 mask per 7 bids
//        (mask waves now 64 words, ~6us, hidden under GEMM); proj templated
//        on xmode so hot path is branch-free gld16 (VGPR back down).
//   conv_w : weights/biases -> f16 in ws
//   conv_x : x fp32/bf16 -> f16 dense in ws (skipped if ws too small)
//   proj   : 1536 GEMM blocks (Q,K,Vt 128x128xBK32) + 2048 mask-pack blocks
//   gemmS  : S = exp(mask? 0 : Q.K^T*scale) f16, bitmask epilogue, phased
//   gemmO  : out = (S @ Vt) / rowsum(S), rowsum via all-ones-B MFMA column

typedef unsigned short u16;
typedef unsigned long long u64;
typedef __attribute__((ext_vector_type(8))) short short8;
typedef __attribute__((ext_vector_type(8))) _Float16 half8;
typedef __attribute__((ext_vector_type(4))) float float4v;

#define S_DIM 2048
#define E_DIM 512
#define NROWS (8 * S_DIM)
#define SCALE 0.044194173824159216f
#define NWORDS ((size_t)8 * S_DIM * S_DIM / 64)   // 524288 u64 words

__device__ __forceinline__ float4v mfma16(short8 a, short8 b, float4v c) {
    return __builtin_amdgcn_mfma_f32_16x16x32_f16(
        __builtin_bit_cast(half8, a), __builtin_bit_cast(half8, b), c, 0, 0, 0);
}
__device__ __forceinline__ float bf2f(unsigned int u) {
    union { unsigned int i; float f; } v; v.i = u << 16; return v.f;
}
__device__ __forceinline__ u16 f2h_bits(float f) {
    union { _Float16 h; u16 u; } v; v.h = (_Float16)f; return v.u;
}
__device__ __forceinline__ float h2f(u16 u) {
    union { u16 u; _Float16 h; } v; v.u = u; return (float)v.h;
}
__device__ __forceinline__ int detect_bf16(const void* wp) {
    const u16* w = (const u16*)wp;
    int cnt = 0;
    for (int i = 0; i < 64; ++i) {
        int e = (w[2 * i] >> 7) & 0xff;
        cnt += (e >= 100 && e <= 131) ? 1 : 0;
    }
    return cnt >= 40;
}
__device__ __forceinline__ void load8(const void* base, size_t idx, int isbf, float* f) {
    if (isbf) {
        uint4 v = *(const uint4*)((const u16*)base + idx);
        f[0] = bf2f(v.x & 0xffffu); f[1] = bf2f(v.x >> 16);
        f[2] = bf2f(v.y & 0xffffu); f[3] = bf2f(v.y >> 16);
        f[4] = bf2f(v.z & 0xffffu); f[5] = bf2f(v.z >> 16);
        f[6] = bf2f(v.w & 0xffffu); f[7] = bf2f(v.w >> 16);
    } else {
        const float* p = (const float*)base + idx;
        float4 a = *(const float4*)p;
        float4 b = *(const float4*)(p + 4);
        f[0] = a.x; f[1] = a.y; f[2] = a.z; f[3] = a.w;
        f[4] = b.x; f[5] = b.y; f[6] = b.z; f[7] = b.w;
    }
}
__device__ __forceinline__ float load1(const void* base, size_t idx, int isbf) {
    return isbf ? bf2f(((const u16*)base)[idx]) : ((const float*)base)[idx];
}

// async 16B global -> LDS (per-lane src, wave-uniform LDS base + lane*16)
__device__ __forceinline__ void gld16(const u16* g, u16* l) {
    __builtin_amdgcn_global_load_lds(
        (const __attribute__((address_space(1))) void*)g,
        (__attribute__((address_space(3))) void*)l, 16, 0, 0);
}

// stage one 16B granule into LDS. C=0: f16 global, async gld16.
// C=1: fp32 global -> f16 (reg-staged). C=2: bf16 global -> f16 (reg-staged).
template<int C>
__device__ __forceinline__ void stage(const void* g, size_t off, u16* lds) {
    if constexpr (C == 0) {
        gld16((const u16*)g + off, lds);
    } else if constexpr (C == 1) {
        const float* p = (const float*)g + off;
        float4 a = *(const float4*)p;
        float4 b = *(const float4*)(p + 4);
        union { u16 h[8]; short8 v; } pk;
        pk.h[0] = f2h_bits(a.x); pk.h[1] = f2h_bits(a.y);
        pk.h[2] = f2h_bits(a.z); pk.h[3] = f2h_bits(a.w);
        pk.h[4] = f2h_bits(b.x); pk.h[5] = f2h_bits(b.y);
        pk.h[6] = f2h_bits(b.z); pk.h[7] = f2h_bits(b.w);
        *(short8*)lds = pk.v;
    } else {
        uint4 v = *(const uint4*)((const u16*)g + off);
        unsigned int uu[4] = {v.x, v.y, v.z, v.w};
        union { u16 h[8]; short8 v8; } pk;
#pragma unroll
        for (int j = 0; j < 4; ++j) {
            pk.h[2 * j]     = f2h_bits(bf2f(uu[j] & 0xffffu));
            pk.h[2 * j + 1] = f2h_bits(bf2f(uu[j] >> 16));
        }
        *(short8*)lds = pk.v8;
    }
}

// ---------------- conversion kernels (read inputs, write ws) ----------------
__global__ __launch_bounds__(256) void conv_w(
    const void* w0, const void* w1, const void* w2,
    const void* b0, const void* b1, const void* b2, u16* wb)
{
    const int z = blockIdx.y;
    const void* w = (z == 0) ? w0 : (z == 1) ? w1 : w2;
    const void* bb = (z == 0) ? b0 : (z == 1) ? b1 : b2;
    const int isbf = detect_bf16(w0);
    const size_t idx = ((size_t)blockIdx.x * 256 + threadIdx.x) * 8;
    float f[8];
    load8(w, idx, isbf, f);
    union { u16 h[8]; uint4 v; } pk;
#pragma unroll
    for (int j = 0; j < 8; ++j) pk.h[j] = f2h_bits(f[j]);
    *(uint4*)(wb + (size_t)z * 262144 + idx) = pk.v;
    if (blockIdx.x == 0) {
        u16* bbase = wb + 3 * 262144 + z * 512;
#pragma unroll
        for (int j = 0; j < 2; ++j) {
            int i = threadIdx.x * 2 + j;
            bbase[i] = f2h_bits(load1(bb, i, isbf));
        }
    }
}

// x fp32/bf16 -> f16 dense [16384][512] in ws. One wave per row.
__global__ __launch_bounds__(256) void conv_x(
    const void* x, const void* wq_orig, u16* xh)
{
    const int w = threadIdx.x >> 6, l = threadIdx.x & 63;
    const int row = blockIdx.x * 4 + w;
    union { u16 h[8]; uint4 v; } pk;
    if (detect_bf16(wq_orig)) {
        uint4 v = *(const uint4*)((const u16*)x + (size_t)row * 512 + l * 8);
        unsigned int uu[4] = {v.x, v.y, v.z, v.w};
#pragma unroll
        for (int j = 0; j < 4; ++j) {
            pk.h[2 * j]     = f2h_bits(bf2f(uu[j] & 0xffffu));
            pk.h[2 * j + 1] = f2h_bits(bf2f(uu[j] >> 16));
        }
    } else {
        const float* src = (const float*)x + (size_t)row * 512 + l * 8;
        float4 a = *(const float4*)src;
        float4 b = *(const float4*)(src + 4);
        pk.h[0] = f2h_bits(a.x); pk.h[1] = f2h_bits(a.y);
        pk.h[2] = f2h_bits(a.z); pk.h[3] = f2h_bits(a.w);
        pk.h[4] = f2h_bits(b.x); pk.h[5] = f2h_bits(b.y);
        pk.h[6] = f2h_bits(b.z); pk.h[7] = f2h_bits(b.w);
    }
    *(uint4*)(xh + (size_t)row * 512 + l * 8) = pk.v;
}

// ---------------- shared GEMM core ----------------
// 128x128 tile, BK=32, 4 waves (2x2 of 64x64), m97 2-barrier K-loop.
// LDS layout: granule(16B) flat = 4*r + (kq ^ ((r>>1)&3))  -> 2-way max conflicts.
template<int ONES, int CA, int CB>
__device__ __forceinline__ void gemm_core(
    const void* __restrict__ A, int sA, const void* __restrict__ B, int sB, int K,
    u16* As, u16* Bs, float4v acc[4][4], float4v accS[4])
{
    const int t = threadIdx.x;
    const int w = t >> 6, l = t & 63;
    const int lane15 = l & 15, quad = l >> 4;
    const int wm = w & 1, wn = w >> 1;

    short8 ones;
#pragma unroll
    for (int j = 0; j < 8; ++j) ones[j] = (short)0x3C00;   // f16 1.0

    for (int kt = 0; kt < K; kt += 32) {
        __syncthreads();
#pragma unroll
        for (int i = 0; i < 2; ++i) {
            const int fg = w * 128 + i * 64 + l;
            const int r = fg >> 2;
            const int kq = (fg & 3) ^ ((r >> 1) & 3);
            stage<CA>(A, (size_t)r * sA + kt + kq * 8, As + fg * 8);
            stage<CB>(B, (size_t)r * sB + kt + kq * 8, Bs + fg * 8);
        }
        __syncthreads();

        short8 af[4], bf[4];
#pragma unroll
        for (int mi = 0; mi < 4; ++mi) {
            const int r = wm * 64 + mi * 16 + lane15;
            af[mi] = *(const short8*)&As[(4 * r + (quad ^ ((r >> 1) & 3))) * 8];
        }
#pragma unroll
        for (int ni = 0; ni < 4; ++ni) {
            const int r = wn * 64 + ni * 16 + lane15;
            bf[ni] = *(const short8*)&Bs[(4 * r + (quad ^ ((r >> 1) & 3))) * 8];
        }
#pragma unroll
        for (int mi = 0; mi < 4; ++mi) {
#pragma unroll
            for (int ni = 0; ni < 4; ++ni)
                acc[mi][ni] = mfma16(af[mi], bf[ni], acc[mi][ni]);
            if (ONES) accS[mi] = mfma16(af[mi], ones, accS[mi]);
        }
    }
}

#define GEMM_PRE()                                                     \
    __shared__ u16 As[4096] __attribute__((aligned(16)));              \
    __shared__ u16 Bs[4096] __attribute__((aligned(16)));              \
    const int t = threadIdx.x;                                         \
    const int w = t >> 6, l = t & 63;                                  \
    const int lane15 = l & 15, quad = l >> 4;                          \
    const int wm = w & 1, wn = w >> 1;                                 \
    (void)l; (void)w;                                                  \
    float4v acc[4][4];                                                 \
    float4v accS[4];                                                   \
    _Pragma("unroll") for (int mi = 0; mi < 4; ++mi) {                 \
        accS[mi] = (float4v){0.f, 0.f, 0.f, 0.f};                      \
        _Pragma("unroll") for (int ni = 0; ni < 4; ++ni)               \
            acc[mi][ni] = (float4v){0.f, 0.f, 0.f, 0.f};               \
    }

// ---------------- proj: Q, K, Vt GEMMs + mask bit-pack, one dispatch --------
// Flat grid 3584 = 512*7. bid%7<3: GEMM (z=bid%7, plane=bid/7, XCD-swizzled).
// bid%7>=3: mask-pack block (2048 total, 64 words/wave, latency-pipelined).
// XM: 0 = xh f16 (gld16 both sides), 1 = x fp32, 2 = x bf16.
template<int XM>
__global__ __launch_bounds__(256) void proj_gemm(
    const void* __restrict__ xsrc, const u16* __restrict__ wb,
    u16* __restrict__ qb, u16* __restrict__ kb, u16* __restrict__ vt,
    const int* __restrict__ mask, u64* __restrict__ mbits)
{
    const int bid = blockIdx.x;
    const int r7 = bid % 7, g7 = bid / 7;
    if (r7 >= 3) {
        // ---- mask pack: block mb of 2048, 4 waves x 64 words ----
        const int mb = g7 * 4 + (r7 - 3);
        const int wv = threadIdx.x >> 6, ml = threadIdx.x & 63;
        const size_t w0 = (size_t)mb * 256 + wv * 64;
#pragma unroll 1
        for (int i = 0; i < 64; i += 4) {
            const int m0 = mask[(w0 + i + 0) * 64 + ml];
            const int m1 = mask[(w0 + i + 1) * 64 + ml];
            const int m2 = mask[(w0 + i + 2) * 64 + ml];
            const int m3 = mask[(w0 + i + 3) * 64 + ml];
            const u64 b0 = __ballot(m0 > 0);
            const u64 b1 = __ballot(m1 > 0);
            const u64 b2 = __ballot(m2 > 0);
            const u64 b3 = __ballot(m3 > 0);
            if (ml == 0) {
                mbits[w0 + i + 0] = b0; mbits[w0 + i + 1] = b1;
                mbits[w0 + i + 2] = b2; mbits[w0 + i + 3] = b3;
            }
        }
        return;
    }

    GEMM_PRE();
    const int z = r7;
    // T1 XCD swizzle within the 512-plane: contiguous tiles per XCD
    const int sl = (g7 & 7) * 64 + (g7 >> 3);
    const int ty = sl >> 2, tx = sl & 3;
    const u16* bias = wb + 3 * 262144 + z * 512;

    int m0, n0;
    if (z < 2) { m0 = ty * 128; n0 = tx * 128; }
    else       { m0 = tx * 128; n0 = ty * 128; }

    if (z < 2) {
        const void* B = wb + (size_t)z * 262144 + (size_t)n0 * 512;
        const void* A = (XM == 1)
            ? (const void*)((const float*)xsrc + (size_t)m0 * 512)
            : (const void*)((const u16*)xsrc + (size_t)m0 * 512);
        gemm_core<0, XM == 0 ? 0 : XM, 0>(A, 512, B, 512, 512, As, Bs, acc, accS);
    } else {
        const void* A = wb + (size_t)2 * 262144 + (size_t)m0 * 512;
        const void* B = (XM == 1)
            ? (const void*)((const float*)xsrc + (size_t)n0 * 512)
            : (const void*)((const u16*)xsrc + (size_t)n0 * 512);
        gemm_core<0, 0, XM == 0 ? 0 : XM>(A, 512, B, 512, 512, As, Bs, acc, accS);
    }

    if (z < 2) {
        u16* dst = z ? kb : qb;
        float bcol[4];
#pragma unroll
        for (int ni = 0; ni < 4; ++ni)
            bcol[ni] = h2f(bias[n0 + wn * 64 + ni * 16 + lane15]);
#pragma unroll
        for (int mi = 0; mi < 4; ++mi)
#pragma unroll
            for (int ni = 0; ni < 4; ++ni)
#pragma unroll
                for (int r = 0; r < 4; ++r) {
                    const int row = m0 + wm * 64 + mi * 16 + quad * 4 + r;
                    const int col = n0 + wn * 64 + ni * 16 + lane15;
                    dst[(size_t)row * 512 + col] = f2h_bits(acc[mi][ni][r] + bcol[ni]);
                }
    } else {
#pragma unroll
        for (int mi = 0; mi < 4; ++mi)
#pragma unroll
            for (int r = 0; r < 4; ++r) {
                const int e = m0 + wm * 64 + mi * 16 + quad * 4 + r;      // 0..511
                const float bias_e = h2f(bias[e]);
#pragma unroll
                for (int ni = 0; ni < 4; ++ni) {
                    const int tok = n0 + wn * 64 + ni * 16 + lane15;
                    vt[((size_t)(tok >> 11) * 512 + e) * 2048 + (tok & 2047)] =
                        f2h_bits(acc[mi][ni][r] + bias_e);
                }
            }
    }
}

// ---------------- gemmS: S = exp(masked(Q.K^T * scale)) f16, phased ----------
__global__ __launch_bounds__(256) void gemmS(
    const u16* __restrict__ qb, const u16* __restrict__ kb,
    const u64* __restrict__ mbits, u16* __restrict__ Sdst, int b0)
{
    GEMM_PRE();
    const int zb = blockIdx.z;
    const int b = b0 + zb;
    // T1 XCD swizzle: plane nwg=256
    const int hh = blockIdx.y * 16 + blockIdx.x;
    const int sl = (hh & 7) * 32 + (hh >> 3);
    const int m0 = (sl >> 4) * 128, n0 = (sl & 15) * 128;
    const u16* A = qb + (size_t)(b * S_DIM + m0) * 512;
    const u16* B = kb + (size_t)(b * S_DIM + n0) * 512;

    gemm_core<0, 0, 0>(A, 512, B, 512, 512, As, Bs, acc, accS);

    u16* Sb = Sdst + (size_t)zb * S_DIM * S_DIM;
    const u64* mb = mbits + (size_t)b * S_DIM * 32 + (n0 >> 6) + wn;
#pragma unroll
    for (int mi = 0; mi < 4; ++mi)
#pragma unroll
        for (int r = 0; r < 4; ++r) {
            const int row = m0 + wm * 64 + mi * 16 + quad * 4 + r;
            const u64 wbits = mb[(size_t)row * 32];
            const int col0 = n0 + wn * 64 + lane15;
#pragma unroll
            for (int ni = 0; ni < 4; ++ni) {
                const int masked = (int)((wbits >> (lane15 + ni * 16)) & 1);
                const float p = masked ? 0.f : __expf(acc[mi][ni][r] * SCALE);
                Sb[(size_t)row * S_DIM + col0 + ni * 16] = f2h_bits(p);
            }
        }
}

// ---------------- gemmO: out = (S @ Vt) / rowsum(S), phased ----------------
__global__ __launch_bounds__(256) void gemmO(
    const u16* __restrict__ Ssrc, const u16* __restrict__ vt,
    float* __restrict__ outp, int b0)
{
    GEMM_PRE();
    const int zb = blockIdx.z;
    const int b = b0 + zb;
    // T1 XCD swizzle: plane nwg=64
    const int hh = blockIdx.y * 4 + blockIdx.x;
    const int sl = (hh & 7) * 8 + (hh >> 3);
    const int m0 = (sl >> 2) * 128, n0 = (sl & 3) * 128;
    const u16* A = Ssrc + (size_t)zb * S_DIM * S_DIM + (size_t)m0 * S_DIM;
    const u16* B = vt + ((size_t)b * 512 + n0) * 2048;

    gemm_core<1, 0, 0>(A, S_DIM, B, S_DIM, S_DIM, As, Bs, acc, accS);

#pragma unroll
    for (int mi = 0; mi < 4; ++mi)
#pragma unroll
        for (int r = 0; r < 4; ++r) {
            const int row = m0 + wm * 64 + mi * 16 + quad * 4 + r;
            const float inv = 1.f / accS[mi][r];
#pragma unroll
            for (int ni = 0; ni < 4; ++ni) {
                const int col = n0 + wn * 64 + ni * 16 + lane15;
                outp[((size_t)b * S_DIM + row) * E_DIM + col] = acc[mi][ni][r] * inv;
            }
        }
}

extern "C" void kernel_launch(void* const* d_in, const int* in_sizes, int n_in,
                              void* d_out, int out_size, void* d_ws, size_t ws_size,
                              hipStream_t stream) {
    const void* x    = d_in[0];
    const int*  mask = (const int*)d_in[1];
    const void* wq   = d_in[2];
    const void* bq   = d_in[3];
    const void* wk   = d_in[4];
    const void* bk   = d_in[5];
    const void* wv   = d_in[6];
    const void* bv   = d_in[7];

    const size_t MB   = 1ull << 20;
    const size_t QSZ  = (size_t)NROWS * E_DIM;          // u16 elems per Q/K/Vt/xh
    const size_t S_PB = (size_t)S_DIM * S_DIM;          // u16 elems per S batch
    const size_t MBITS_B = NWORDS * 8;                  // 4 MB

    u16* wb   = (u16*)d_ws;                             // 2 MB (weights+bias f16)
    u16* qb   = (u16*)((char*)d_ws + 2 * MB);
    u16* kb   = qb + QSZ;
    u16* vtb  = kb + QSZ;
    u64* mbit = (u64*)(vtb + QSZ);                      // 4 MB bitmask
    u16* xh   = (u16*)((char*)mbit + MBITS_B);          // 16.8 MB f16 x (dead after proj)
    u16* sS   = xh;                                     // S scratch aliases xh

    const size_t fixed = 2 * MB + 3 * QSZ * 2 + MBITS_B;      // 56.4 MB (pre-xh)
    const size_t avail = (ws_size > fixed) ? (ws_size - fixed) : 0;
    const int use_xh = avail >= (QSZ * 2 + 2 * S_PB);   // xh + >=1 S batch comfortably
    const size_t availB = avail / (S_PB * 2);
    const int P = (availB >= 8) ? 8 : (availB >= 4) ? 4 : (availB >= 2) ? 2 : 1;

    conv_w<<<dim3(128, 3), 256, 0, stream>>>(wq, wk, wv, bq, bk, bv, wb);

    if (use_xh) {
        conv_x<<<NROWS / 4, 256, 0, stream>>>(x, wq, xh);
        proj_gemm<0><<<3584, 256, 0, stream>>>(xh, wb, qb, kb, vtb, mask, mbit);
    } else {
        // small-ws fallback: on-the-fly x conversion; dtype via in_sizes
        // (x fp32 = NROWS*512*4 bytes; 16-bit input = half that).
        if (in_sizes[0] >= (int)(NROWS * 512 * 4))
            proj_gemm<1><<<3584, 256, 0, stream>>>(x, wb, qb, kb, vtb, mask, mbit);
        else
            proj_gemm<2><<<3584, 256, 0, stream>>>(x, wb, qb, kb, vtb, mask, mbit);
    }

    for (int p = 0; p < 8; p += P) {
        gemmS<<<dim3(16, 16, P), 256, 0, stream>>>(qb, kb, mbit, sS, p);
        gemmO<<<dim3(4, 16, P), 256, 0, stream>>>(sS, vtb, (float*)d_out, p);
    }
}

// Round 6
// 198.821 us; speedup vs baseline: 1.1508x; 1.1508x over previous
//
#include <hip/hip_runtime.h>
#include <hip/hip_bf16.h>
#include <hip/hip_fp16.h>

// MHAHead B=8,S=2048,E=512. R11: decouple mask from proj; pack inside gemmS.
//   R8-R10 lesson: any scheme giving the 134MB mask stream its own serial
//   pass or fusing it into proj costs 15-25us; R7 (mask inside gemmS) was
//   fastest (224us) because gemmS's K-loop hides the stream -- its only sin
//   was 64 strided HBM epilogue loads per thread (latency tail).
//   R11: proj = pure GEMM on xh (f16) + XCD swizzle (never measured clean);
//        gemmS prologue: per wave 4x16 coalesced 256B mask loads ->
//        __ballot -> 2KB LDS bitwords; epilogue reads broadcast LDS.
//   conv_w : weights/biases -> f16 in ws
//   conv_x : x fp32/bf16 -> f16 dense in ws (skipped if ws too small)
//   proj   : uni GEMM 128x128xBK32 (Q,K,Vt), all-gld16 staging
//   gemmS  : S = exp(mask? 0 : Q.K^T*scale) f16, in-kernel mask pack, phased
//   gemmO  : out = (S @ Vt) / rowsum(S), rowsum via all-ones-B MFMA column

typedef unsigned short u16;
typedef unsigned long long u64;
typedef __attribute__((ext_vector_type(8))) short short8;
typedef __attribute__((ext_vector_type(8))) _Float16 half8;
typedef __attribute__((ext_vector_type(4))) float float4v;

#define S_DIM 2048
#define E_DIM 512
#define NROWS (8 * S_DIM)
#define SCALE 0.044194173824159216f

__device__ __forceinline__ float4v mfma16(short8 a, short8 b, float4v c) {
    return __builtin_amdgcn_mfma_f32_16x16x32_f16(
        __builtin_bit_cast(half8, a), __builtin_bit_cast(half8, b), c, 0, 0, 0);
}
__device__ __forceinline__ float bf2f(unsigned int u) {
    union { unsigned int i; float f; } v; v.i = u << 16; return v.f;
}
__device__ __forceinline__ u16 f2h_bits(float f) {
    union { _Float16 h; u16 u; } v; v.h = (_Float16)f; return v.u;
}
__device__ __forceinline__ float h2f(u16 u) {
    union { u16 u; _Float16 h; } v; v.u = u; return (float)v.h;
}
__device__ __forceinline__ int detect_bf16(const void* wp) {
    const u16* w = (const u16*)wp;
    int cnt = 0;
    for (int i = 0; i < 64; ++i) {
        int e = (w[2 * i] >> 7) & 0xff;
        cnt += (e >= 100 && e <= 131) ? 1 : 0;
    }
    return cnt >= 40;
}
__device__ __forceinline__ void load8(const void* base, size_t idx, int isbf, float* f) {
    if (isbf) {
        uint4 v = *(const uint4*)((const u16*)base + idx);
        f[0] = bf2f(v.x & 0xffffu); f[1] = bf2f(v.x >> 16);
        f[2] = bf2f(v.y & 0xffffu); f[3] = bf2f(v.y >> 16);
        f[4] = bf2f(v.z & 0xffffu); f[5] = bf2f(v.z >> 16);
        f[6] = bf2f(v.w & 0xffffu); f[7] = bf2f(v.w >> 16);
    } else {
        const float* p = (const float*)base + idx;
        float4 a = *(const float4*)p;
        float4 b = *(const float4*)(p + 4);
        f[0] = a.x; f[1] = a.y; f[2] = a.z; f[3] = a.w;
        f[4] = b.x; f[5] = b.y; f[6] = b.z; f[7] = b.w;
    }
}
__device__ __forceinline__ float load1(const void* base, size_t idx, int isbf) {
    return isbf ? bf2f(((const u16*)base)[idx]) : ((const float*)base)[idx];
}

// async 16B global -> LDS (per-lane src, wave-uniform LDS base + lane*16)
__device__ __forceinline__ void gld16(const u16* g, u16* l) {
    __builtin_amdgcn_global_load_lds(
        (const __attribute__((address_space(1))) void*)g,
        (__attribute__((address_space(3))) void*)l, 16, 0, 0);
}

// stage one 16B granule into LDS. C=0: f16 global, async gld16.
// C=1: fp32 global -> f16 (reg-staged). C=2: bf16 global -> f16 (reg-staged).
template<int C>
__device__ __forceinline__ void stage(const void* g, size_t off, u16* lds) {
    if constexpr (C == 0) {
        gld16((const u16*)g + off, lds);
    } else if constexpr (C == 1) {
        const float* p = (const float*)g + off;
        float4 a = *(const float4*)p;
        float4 b = *(const float4*)(p + 4);
        union { u16 h[8]; short8 v; } pk;
        pk.h[0] = f2h_bits(a.x); pk.h[1] = f2h_bits(a.y);
        pk.h[2] = f2h_bits(a.z); pk.h[3] = f2h_bits(a.w);
        pk.h[4] = f2h_bits(b.x); pk.h[5] = f2h_bits(b.y);
        pk.h[6] = f2h_bits(b.z); pk.h[7] = f2h_bits(b.w);
        *(short8*)lds = pk.v;
    } else {
        uint4 v = *(const uint4*)((const u16*)g + off);
        unsigned int uu[4] = {v.x, v.y, v.z, v.w};
        union { u16 h[8]; short8 v8; } pk;
#pragma unroll
        for (int j = 0; j < 4; ++j) {
            pk.h[2 * j]     = f2h_bits(bf2f(uu[j] & 0xffffu));
            pk.h[2 * j + 1] = f2h_bits(bf2f(uu[j] >> 16));
        }
        *(short8*)lds = pk.v8;
    }
}

// ---------------- conversion kernels (read inputs, write ws) ----------------
__global__ __launch_bounds__(256) void conv_w(
    const void* w0, const void* w1, const void* w2,
    const void* b0, const void* b1, const void* b2, u16* wb)
{
    const int z = blockIdx.y;
    const void* w = (z == 0) ? w0 : (z == 1) ? w1 : w2;
    const void* bb = (z == 0) ? b0 : (z == 1) ? b1 : b2;
    const int isbf = detect_bf16(w0);
    const size_t idx = ((size_t)blockIdx.x * 256 + threadIdx.x) * 8;
    float f[8];
    load8(w, idx, isbf, f);
    union { u16 h[8]; uint4 v; } pk;
#pragma unroll
    for (int j = 0; j < 8; ++j) pk.h[j] = f2h_bits(f[j]);
    *(uint4*)(wb + (size_t)z * 262144 + idx) = pk.v;
    if (blockIdx.x == 0) {
        u16* bbase = wb + 3 * 262144 + z * 512;
#pragma unroll
        for (int j = 0; j < 2; ++j) {
            int i = threadIdx.x * 2 + j;
            bbase[i] = f2h_bits(load1(bb, i, isbf));
        }
    }
}

// x fp32/bf16 -> f16 dense [16384][512] in ws. One wave per row.
__global__ __launch_bounds__(256) void conv_x(
    const void* x, const void* wq_orig, u16* xh)
{
    const int w = threadIdx.x >> 6, l = threadIdx.x & 63;
    const int row = blockIdx.x * 4 + w;
    union { u16 h[8]; uint4 v; } pk;
    if (detect_bf16(wq_orig)) {
        uint4 v = *(const uint4*)((const u16*)x + (size_t)row * 512 + l * 8);
        unsigned int uu[4] = {v.x, v.y, v.z, v.w};
#pragma unroll
        for (int j = 0; j < 4; ++j) {
            pk.h[2 * j]     = f2h_bits(bf2f(uu[j] & 0xffffu));
            pk.h[2 * j + 1] = f2h_bits(bf2f(uu[j] >> 16));
        }
    } else {
        const float* src = (const float*)x + (size_t)row * 512 + l * 8;
        float4 a = *(const float4*)src;
        float4 b = *(const float4*)(src + 4);
        pk.h[0] = f2h_bits(a.x); pk.h[1] = f2h_bits(a.y);
        pk.h[2] = f2h_bits(a.z); pk.h[3] = f2h_bits(a.w);
        pk.h[4] = f2h_bits(b.x); pk.h[5] = f2h_bits(b.y);
        pk.h[6] = f2h_bits(b.z); pk.h[7] = f2h_bits(b.w);
    }
    *(uint4*)(xh + (size_t)row * 512 + l * 8) = pk.v;
}

// ---------------- shared GEMM core ----------------
// 128x128 tile, BK=32, 4 waves (2x2 of 64x64), m97 2-barrier K-loop.
// LDS layout: granule(16B) flat = 4*r + (kq ^ ((r>>1)&3))  -> 2-way max conflicts.
template<int ONES, int CA, int CB>
__device__ __forceinline__ void gemm_core(
    const void* __restrict__ A, int sA, const void* __restrict__ B, int sB, int K,
    u16* As, u16* Bs, float4v acc[4][4], float4v accS[4])
{
    const int t = threadIdx.x;
    const int w = t >> 6, l = t & 63;
    const int lane15 = l & 15, quad = l >> 4;
    const int wm = w & 1, wn = w >> 1;

    short8 ones;
#pragma unroll
    for (int j = 0; j < 8; ++j) ones[j] = (short)0x3C00;   // f16 1.0

    for (int kt = 0; kt < K; kt += 32) {
        __syncthreads();
#pragma unroll
        for (int i = 0; i < 2; ++i) {
            const int fg = w * 128 + i * 64 + l;
            const int r = fg >> 2;
            const int kq = (fg & 3) ^ ((r >> 1) & 3);
            stage<CA>(A, (size_t)r * sA + kt + kq * 8, As + fg * 8);
            stage<CB>(B, (size_t)r * sB + kt + kq * 8, Bs + fg * 8);
        }
        __syncthreads();

        short8 af[4], bf[4];
#pragma unroll
        for (int mi = 0; mi < 4; ++mi) {
            const int r = wm * 64 + mi * 16 + lane15;
            af[mi] = *(const short8*)&As[(4 * r + (quad ^ ((r >> 1) & 3))) * 8];
        }
#pragma unroll
        for (int ni = 0; ni < 4; ++ni) {
            const int r = wn * 64 + ni * 16 + lane15;
            bf[ni] = *(const short8*)&Bs[(4 * r + (quad ^ ((r >> 1) & 3))) * 8];
        }
#pragma unroll
        for (int mi = 0; mi < 4; ++mi) {
#pragma unroll
            for (int ni = 0; ni < 4; ++ni)
                acc[mi][ni] = mfma16(af[mi], bf[ni], acc[mi][ni]);
            if (ONES) accS[mi] = mfma16(af[mi], ones, accS[mi]);
        }
    }
}

#define GEMM_PRE()                                                     \
    __shared__ u16 As[4096] __attribute__((aligned(16)));              \
    __shared__ u16 Bs[4096] __attribute__((aligned(16)));              \
    const int t = threadIdx.x;                                         \
    const int w = t >> 6, l = t & 63;                                  \
    const int lane15 = l & 15, quad = l >> 4;                          \
    const int wm = w & 1, wn = w >> 1;                                 \
    (void)l; (void)w;                                                  \
    float4v acc[4][4];                                                 \
    float4v accS[4];                                                   \
    _Pragma("unroll") for (int mi = 0; mi < 4; ++mi) {                 \
        accS[mi] = (float4v){0.f, 0.f, 0.f, 0.f};                      \
        _Pragma("unroll") for (int ni = 0; ni < 4; ++ni)               \
            acc[mi][ni] = (float4v){0.f, 0.f, 0.f, 0.f};               \
    }

// ---------------- proj: Q, K, Vt (pure GEMM, no mask) ----------------
// XM: 0 = xh f16 (gld16 both sides), 1 = x fp32, 2 = x bf16.
// z<2: A = x[m0..], B = wb[z][n0..]; C -> Q or K (f16, ws)
// z=2: A = wb[2][m0..], B = x[n0..]; C -> Vt (f16, ws)
template<int XM>
__global__ __launch_bounds__(256) void proj_gemm(
    const void* __restrict__ xsrc, const u16* __restrict__ wb,
    u16* __restrict__ qb, u16* __restrict__ kb, u16* __restrict__ vt)
{
    GEMM_PRE();
    const int z = blockIdx.z;
    // T1 XCD swizzle within the 512-plane (nwg %8==0, bijective)
    const int hh = blockIdx.y * 4 + blockIdx.x;
    const int sl = (hh & 7) * 64 + (hh >> 3);
    const int ty = sl >> 2, tx = sl & 3;
    const u16* bias = wb + 3 * 262144 + z * 512;

    int m0, n0;
    if (z < 2) { m0 = ty * 128; n0 = tx * 128; }
    else       { m0 = tx * 128; n0 = ty * 128; }

    if (z < 2) {
        const void* B = wb + (size_t)z * 262144 + (size_t)n0 * 512;
        const void* A = (XM == 1)
            ? (const void*)((const float*)xsrc + (size_t)m0 * 512)
            : (const void*)((const u16*)xsrc + (size_t)m0 * 512);
        gemm_core<0, XM == 0 ? 0 : XM, 0>(A, 512, B, 512, 512, As, Bs, acc, accS);
    } else {
        const void* A = wb + (size_t)2 * 262144 + (size_t)m0 * 512;
        const void* B = (XM == 1)
            ? (const void*)((const float*)xsrc + (size_t)n0 * 512)
            : (const void*)((const u16*)xsrc + (size_t)n0 * 512);
        gemm_core<0, 0, XM == 0 ? 0 : XM>(A, 512, B, 512, 512, As, Bs, acc, accS);
    }

    if (z < 2) {
        u16* dst = z ? kb : qb;
        float bcol[4];
#pragma unroll
        for (int ni = 0; ni < 4; ++ni)
            bcol[ni] = h2f(bias[n0 + wn * 64 + ni * 16 + lane15]);
#pragma unroll
        for (int mi = 0; mi < 4; ++mi)
#pragma unroll
            for (int ni = 0; ni < 4; ++ni)
#pragma unroll
                for (int r = 0; r < 4; ++r) {
                    const int row = m0 + wm * 64 + mi * 16 + quad * 4 + r;
                    const int col = n0 + wn * 64 + ni * 16 + lane15;
                    dst[(size_t)row * 512 + col] = f2h_bits(acc[mi][ni][r] + bcol[ni]);
                }
    } else {
#pragma unroll
        for (int mi = 0; mi < 4; ++mi)
#pragma unroll
            for (int r = 0; r < 4; ++r) {
                const int e = m0 + wm * 64 + mi * 16 + quad * 4 + r;      // 0..511
                const float bias_e = h2f(bias[e]);
#pragma unroll
                for (int ni = 0; ni < 4; ++ni) {
                    const int tok = n0 + wn * 64 + ni * 16 + lane15;
                    vt[((size_t)(tok >> 11) * 512 + e) * 2048 + (tok & 2047)] =
                        f2h_bits(acc[mi][ni][r] + bias_e);
                }
            }
    }
}

// ---------------- gemmS: S = exp(masked(Q.K^T * scale)) f16, phased ----------
// Prologue: each wave ballot-packs its 64x64 mask quadrant (4 rounds of 16
// coalesced 256B loads, held in flight) into 64 u64 LDS words. Epilogue reads
// broadcast LDS bits -- no global mask access at tile end.
__global__ __launch_bounds__(256) void gemmS(
    const u16* __restrict__ qb, const u16* __restrict__ kb,
    const int* __restrict__ mask, u16* __restrict__ Sdst, int b0)
{
    GEMM_PRE();
    __shared__ u64 maskw[256];          // [wave][row_local]
    const int zb = blockIdx.z;
    const int b = b0 + zb;
    // T1 XCD swizzle: plane nwg=256
    const int hh = blockIdx.y * 16 + blockIdx.x;
    const int sl = (hh & 7) * 32 + (hh >> 3);
    const int m0 = (sl >> 4) * 128, n0 = (sl & 15) * 128;

    {   // mask pack: wave (wm,wn) covers rows m0+wm*64.., cols n0+wn*64..
        const int* mrow = mask + ((size_t)b * S_DIM + m0 + wm * 64) * S_DIM
                               + n0 + wn * 64 + l;
#pragma unroll
        for (int rnd = 0; rnd < 4; ++rnd) {
            int v[16];
#pragma unroll
            for (int i = 0; i < 16; ++i)
                v[i] = mrow[(size_t)(rnd * 16 + i) * S_DIM];
            u64 bb[16];
#pragma unroll
            for (int i = 0; i < 16; ++i)
                bb[i] = __ballot(v[i] > 0);
            if (l == 0) {
#pragma unroll
                for (int i = 0; i < 16; ++i)
                    maskw[w * 64 + rnd * 16 + i] = bb[i];
            }
        }
    }

    const u16* A = qb + (size_t)(b * S_DIM + m0) * 512;
    const u16* B = kb + (size_t)(b * S_DIM + n0) * 512;
    gemm_core<0, 0, 0>(A, 512, B, 512, 512, As, Bs, acc, accS);

    u16* Sb = Sdst + (size_t)zb * S_DIM * S_DIM;
#pragma unroll
    for (int mi = 0; mi < 4; ++mi)
#pragma unroll
        for (int r = 0; r < 4; ++r) {
            const int row = m0 + wm * 64 + mi * 16 + quad * 4 + r;
            const u64 wbits = maskw[w * 64 + mi * 16 + quad * 4 + r];
            const int col0 = n0 + wn * 64 + lane15;
#pragma unroll
            for (int ni = 0; ni < 4; ++ni) {
                const int masked = (int)((wbits >> (lane15 + ni * 16)) & 1);
                const float p = masked ? 0.f : __expf(acc[mi][ni][r] * SCALE);
                Sb[(size_t)row * S_DIM + col0 + ni * 16] = f2h_bits(p);
            }
        }
}

// ---------------- gemmO: out = (S @ Vt) / rowsum(S), phased ----------------
__global__ __launch_bounds__(256) void gemmO(
    const u16* __restrict__ Ssrc, const u16* __restrict__ vt,
    float* __restrict__ outp, int b0)
{
    GEMM_PRE();
    const int zb = blockIdx.z;
    const int b = b0 + zb;
    // T1 XCD swizzle: plane nwg=64
    const int hh = blockIdx.y * 4 + blockIdx.x;
    const int sl = (hh & 7) * 8 + (hh >> 3);
    const int m0 = (sl >> 2) * 128, n0 = (sl & 3) * 128;
    const u16* A = Ssrc + (size_t)zb * S_DIM * S_DIM + (size_t)m0 * S_DIM;
    const u16* B = vt + ((size_t)b * 512 + n0) * 2048;

    gemm_core<1, 0, 0>(A, S_DIM, B, S_DIM, S_DIM, As, Bs, acc, accS);

#pragma unroll
    for (int mi = 0; mi < 4; ++mi)
#pragma unroll
        for (int r = 0; r < 4; ++r) {
            const int row = m0 + wm * 64 + mi * 16 + quad * 4 + r;
            const float inv = 1.f / accS[mi][r];
#pragma unroll
            for (int ni = 0; ni < 4; ++ni) {
                const int col = n0 + wn * 64 + ni * 16 + lane15;
                outp[((size_t)b * S_DIM + row) * E_DIM + col] = acc[mi][ni][r] * inv;
            }
        }
}

extern "C" void kernel_launch(void* const* d_in, const int* in_sizes, int n_in,
                              void* d_out, int out_size, void* d_ws, size_t ws_size,
                              hipStream_t stream) {
    const void* x    = d_in[0];
    const int*  mask = (const int*)d_in[1];
    const void* wq   = d_in[2];
    const void* bq   = d_in[3];
    const void* wk   = d_in[4];
    const void* bk   = d_in[5];
    const void* wv   = d_in[6];
    const void* bv   = d_in[7];

    const size_t MB   = 1ull << 20;
    const size_t QSZ  = (size_t)NROWS * E_DIM;          // u16 elems per Q/K/Vt/xh
    const size_t S_PB = (size_t)S_DIM * S_DIM;          // u16 elems per S batch

    u16* wb   = (u16*)d_ws;                             // 2 MB (weights+bias f16)
    u16* qb   = (u16*)((char*)d_ws + 2 * MB);
    u16* kb   = qb + QSZ;
    u16* vtb  = kb + QSZ;
    u16* xh   = vtb + QSZ;                              // 16.8 MB f16 x (dead after proj)
    u16* sS   = xh;                                     // S scratch aliases xh

    const size_t fixed = 2 * MB + 3 * QSZ * 2;          // 52.4 MB (pre-xh)
    const size_t avail = (ws_size > fixed) ? (ws_size - fixed) : 0;
    const int use_xh = avail >= (QSZ * 2 + 2 * S_PB);   // xh + >=2 S batches
    const size_t availB = avail / (S_PB * 2);
    const int P = (availB >= 8) ? 8 : (availB >= 4) ? 4 : (availB >= 2) ? 2 : 1;

    conv_w<<<dim3(128, 3), 256, 0, stream>>>(wq, wk, wv, bq, bk, bv, wb);

    if (use_xh) {
        conv_x<<<NROWS / 4, 256, 0, stream>>>(x, wq, xh);
        proj_gemm<0><<<dim3(4, 128, 3), 256, 0, stream>>>(xh, wb, qb, kb, vtb);
    } else {
        // small-ws fallback: on-the-fly x conversion; dtype via in_sizes
        // (x fp32 = NROWS*512*4 bytes; 16-bit input = half that).
        if (in_sizes[0] >= (int)(NROWS * 512 * 4))
            proj_gemm<1><<<dim3(4, 128, 3), 256, 0, stream>>>(x, wb, qb, kb, vtb);
        else
            proj_gemm<2><<<dim3(4, 128, 3), 256, 0, stream>>>(x, wb, qb, kb, vtb);
    }

    for (int p = 0; p < 8; p += P) {
        gemmS<<<dim3(16, 16, P), 256, 0, stream>>>(qb, kb, mask, sS, p);
        gemmO<<<dim3(4, 16, P), 256, 0, stream>>>(sS, vtb, (float*)d_out, p);
    }
}